// Round 1
// baseline (1371.733 us; speedup 1.0000x reference)
//
#include <hip/hip_runtime.h>
#include <stdint.h>

// Problem constants (fixed by the reference: [16, 84, 256, 256] f32)
#define BATCH   16
#define C_CLS   80
#define CH_TOT  84
#define HDIM    256
#define WDIM    256
#define HW      65536            // 256*256
#define NCLS    (C_CLS * HW)     // 5,242,880 class elements per batch
#define NQ      (NCLS / 4)       // 1,310,720 float4 quads per batch
#define TOPK    100
#define MIN_CONF 0.1f

// Static thresholds (monotone-mapped bit patterns).
// mono(u) = u ^ ( (int(u)>>31) | 0x80000000 )  -- order-preserving uint map for floats
#define T0_MONO 0xBF7FBE77u   // mono(bits(0.999f))  -> expected ~5243 candidates/batch
#define T1_MONO 0xBF7D70A4u   // mono(bits(0.99f))   -> histogram lower bound

typedef unsigned long long u64;

__device__ __forceinline__ uint32_t mono32(uint32_t u) {
    return u ^ ((uint32_t)((int32_t)u >> 31) | 0x80000000u);
}
__device__ __forceinline__ u64 umax64(u64 a, u64 b) { return a > b ? a : b; }

// ---------------------------------------------------------------------------
// K1: single streaming pass over the class region.
//  - histogram of elements >= 0.99 (fine bins, global atomics; safety net)
//  - collect 64-bit keys of elements >= 0.999 into per-batch candidate buffer
// ---------------------------------------------------------------------------
__global__ __launch_bounds__(256)
void k_hist_collect(const float* __restrict__ in, uint32_t* __restrict__ hist,
                    uint32_t* __restrict__ cnt0, u64* __restrict__ cand0,
                    int cap, int hbins, int hshift, int bpb) {
    const int b = blockIdx.y;
    const float4* __restrict__ src =
        (const float4*)(in + (size_t)b * CH_TOT * HW);
    uint32_t* __restrict__ histb = hist + (size_t)b * hbins;
    const int qper = NQ / (bpb * 256);          // quads per thread
    const int q0 = blockIdx.x * (NQ / bpb) + threadIdx.x;

    for (int i = 0; i < qper; ++i) {
        const int q = q0 + i * 256;
        float4 v = src[q];
        uint32_t us[4] = { __float_as_uint(v.x), __float_as_uint(v.y),
                           __float_as_uint(v.z), __float_as_uint(v.w) };
        const uint32_t idx0 = (uint32_t)q * 4u;
#pragma unroll
        for (int j = 0; j < 4; ++j) {
            uint32_t m = mono32(us[j]);
            if (m >= T1_MONO) {
                uint32_t bin = (m - T1_MONO) >> hshift;
                if (bin >= (uint32_t)hbins) bin = hbins - 1;
                atomicAdd(&histb[bin], 1u);
                if (m >= T0_MONO) {
                    uint32_t slot = atomicAdd(&cnt0[b], 1u);
                    if (slot < (uint32_t)cap) {
                        u64 key = ((u64)m << 32) | (u64)(0xFFFFFFFFu - (idx0 + j));
                        cand0[(size_t)b * cap + slot] = key;
                    }
                }
            }
        }
    }
}

// ---------------------------------------------------------------------------
// K2: per-batch decision. meta = {use_fallback, n0, fallback_thresh, 0}
// ---------------------------------------------------------------------------
__global__ __launch_bounds__(256)
void k_meta(const uint32_t* __restrict__ hist, const uint32_t* __restrict__ cnt0,
            uint4* __restrict__ meta, int cap, int hbins, int hshift) {
    const int b = blockIdx.x;
    const uint32_t c0 = cnt0[b];
    if (c0 >= TOPK && c0 <= (uint32_t)cap) {
        if (threadIdx.x == 0) meta[b] = make_uint4(0u, c0, 0u, 0u);
        return;
    }
    // Fallback: suffix-scan the histogram from the top to find a threshold
    // with cumulative count >= TOPK.
    __shared__ uint32_t psum[256];
    const uint32_t* hb = hist + (size_t)b * hbins;
    const int per = hbins / 256;
    uint32_t s = 0;
    for (int i = 0; i < per; ++i) s += hb[threadIdx.x * per + i];
    psum[threadIdx.x] = s;
    __syncthreads();
    if (threadIdx.x == 0) {
        uint32_t cum = 0, thresh = 0;
        int done = 0;
        for (int t = 255; t >= 0 && !done; --t) {
            if (cum + psum[t] >= TOPK) {
                for (int i = per - 1; i >= 0; --i) {
                    const int bin = t * per + i;
                    cum += hb[bin];
                    if (cum >= TOPK) {
                        thresh = T1_MONO + ((uint32_t)bin << hshift);
                        done = 1;
                        break;
                    }
                }
            } else {
                cum += psum[t];
            }
        }
        if (!done) thresh = 0u;  // degenerate data: collect everything (capped)
        meta[b] = make_uint4(1u, 0u, thresh, 0u);
    }
}

// ---------------------------------------------------------------------------
// K3: fallback collect (early-exits when buffer 0 suffices — the common case)
// ---------------------------------------------------------------------------
__global__ __launch_bounds__(256)
void k_collect2(const float* __restrict__ in, const uint4* __restrict__ meta,
                uint32_t* __restrict__ cnt1, u64* __restrict__ cand1,
                int cap, int bpb) {
    const int b = blockIdx.y;
    const uint4 m = meta[b];
    if (m.x != 1u) return;
    const uint32_t thresh = m.z;
    const float4* __restrict__ src =
        (const float4*)(in + (size_t)b * CH_TOT * HW);
    const int qper = NQ / (bpb * 256);
    const int q0 = blockIdx.x * (NQ / bpb) + threadIdx.x;
    for (int i = 0; i < qper; ++i) {
        const int q = q0 + i * 256;
        float4 v = src[q];
        uint32_t us[4] = { __float_as_uint(v.x), __float_as_uint(v.y),
                           __float_as_uint(v.z), __float_as_uint(v.w) };
        const uint32_t idx0 = (uint32_t)q * 4u;
#pragma unroll
        for (int j = 0; j < 4; ++j) {
            uint32_t mo = mono32(us[j]);
            if (mo >= thresh) {
                uint32_t slot = atomicAdd(&cnt1[b], 1u);
                if (slot < (uint32_t)cap) {
                    u64 key = ((u64)mo << 32) | (u64)(0xFFFFFFFFu - (idx0 + j));
                    cand1[(size_t)b * cap + slot] = key;
                }
            }
        }
    }
}

// ---------------------------------------------------------------------------
// K4: per-batch exact top-100 (desc by 64-bit key) + decode + gather + write.
// Cached-local-max argmax: per iteration only the winning thread rescans.
// ---------------------------------------------------------------------------
template <int CAP>
__global__ __launch_bounds__(512)
void k_final(const float* __restrict__ in, const uint4* __restrict__ meta,
             const uint32_t* __restrict__ cnt1, const u64* __restrict__ cand0,
             const u64* __restrict__ cand1, float* __restrict__ out) {
    constexpr int NT = 512;
    constexpr int KPT = CAP / NT;
    const int b = blockIdx.x;
    const int t = threadIdx.x;
    const int wave = t >> 6, lane = t & 63;

    const uint4 m = meta[b];
    const u64* cand;
    uint32_t n;
    if (m.x == 0u) { cand = cand0 + (size_t)b * CAP; n = m.y; }
    else           { cand = cand1 + (size_t)b * CAP; n = min(cnt1[b], (uint32_t)CAP); }

    u64 key[KPT];
#pragma unroll
    for (int j = 0; j < KPT; ++j) {
        const uint32_t i = (uint32_t)(t + j * NT);   // coalesced
        key[j] = (i < n) ? cand[i] : 0ull;
    }
    u64 lmax = 0;
#pragma unroll
    for (int j = 0; j < KPT; ++j) lmax = umax64(lmax, key[j]);

    __shared__ u64 wmax[NT / 64];
    __shared__ u64 gsel;
    __shared__ u64 sel[TOPK];

    for (int r = 0; r < TOPK; ++r) {
        u64 wm = lmax;
#pragma unroll
        for (int d = 1; d < 64; d <<= 1) wm = umax64(wm, __shfl_xor(wm, d, 64));
        if (lane == 0) wmax[wave] = wm;
        __syncthreads();
        if (t == 0) {
            u64 g = wmax[0];
#pragma unroll
            for (int w2 = 1; w2 < NT / 64; ++w2) g = umax64(g, wmax[w2]);
            gsel = g;
            sel[r] = g;
        }
        __syncthreads();
        const u64 g = gsel;
        if (g != 0ull && lmax == g) {   // keys are distinct: exactly one owner
#pragma unroll
            for (int j = 0; j < KPT; ++j) if (key[j] == g) key[j] = 0ull;
            lmax = 0;
#pragma unroll
            for (int j = 0; j < KPT; ++j) lmax = umax64(lmax, key[j]);
        }
    }
    __syncthreads();

    if (t < TOPK) {
        const u64 kk = sel[t];
        float* o = out + ((size_t)b * TOPK + t) * 6;
        float vals[6] = {0.f, 0.f, 0.f, 0.f, 0.f, 0.f};
        if (kk != 0ull) {
            const uint32_t mo = (uint32_t)(kk >> 32);
            const uint32_t bits = (mo & 0x80000000u) ? (mo & 0x7FFFFFFFu) : ~mo;
            const float conf = __uint_as_float(bits);
            if (conf >= MIN_CONF) {
                const uint32_t idx = 0xFFFFFFFFu - (uint32_t)(kk & 0xFFFFFFFFu);
                const uint32_t cls = idx >> 16;
                const uint32_t yy = (idx >> 8) & 255u;
                const uint32_t xx = idx & 255u;
                const float* base = in + (size_t)b * CH_TOT * HW + yy * WDIM + xx;
                const float offy = base[(size_t)(C_CLS + 0) * HW];
                const float offx = base[(size_t)(C_CLS + 1) * HW];
                const float hh   = base[(size_t)(C_CLS + 2) * HW];
                const float ww   = base[(size_t)(C_CLS + 3) * HW];
                vals[0] = (float)yy + offy;
                vals[1] = (float)xx + offx;
                vals[2] = hh;
                vals[3] = ww;
                vals[4] = (float)cls;
                vals[5] = conf;
            }
        }
#pragma unroll
        for (int j = 0; j < 6; ++j) o[j] = vals[j];
    }
}

// ---------------------------------------------------------------------------
extern "C" void kernel_launch(void* const* d_in, const int* in_sizes, int n_in,
                              void* d_out, int out_size, void* d_ws, size_t ws_size,
                              hipStream_t stream) {
    const float* in = (const float*)d_in[0];
    float* out = (float*)d_out;
    uint8_t* ws = (uint8_t*)d_ws;

    const int bpb = 320;  // blocks per batch for the streaming passes

    // Primary config needs: hist 16*4096*4 + counters 128 + meta 256 + 2 cand
    // buffers of 16*8192*8 = 2,621,568 B total.
    const size_t need_big = (size_t)16 * 4096 * 4 + 128 + 256 + 2ull * 16 * 8192 * 8;

    if (ws_size >= need_big) {
        const int CAP = 8192, HBINS = 4096, HSHIFT = 6;
        const size_t histB = (size_t)BATCH * HBINS * 4;
        uint32_t* hist = (uint32_t*)ws;
        uint32_t* cnt0 = (uint32_t*)(ws + histB);
        uint32_t* cnt1 = (uint32_t*)(ws + histB + 64);
        uint4*    meta = (uint4*)(ws + histB + 128);
        u64* cand0 = (u64*)(ws + histB + 128 + 256);
        u64* cand1 = (u64*)(ws + histB + 128 + 256 + (size_t)BATCH * CAP * 8);

        hipMemsetAsync(d_ws, 0, histB + 128, stream);
        dim3 gs(bpb, BATCH), blk(256);
        k_hist_collect<<<gs, blk, 0, stream>>>(in, hist, cnt0, cand0, CAP, HBINS, HSHIFT, bpb);
        k_meta<<<BATCH, 256, 0, stream>>>(hist, cnt0, meta, CAP, HBINS, HSHIFT);
        k_collect2<<<gs, blk, 0, stream>>>(in, meta, cnt1, cand1, CAP, bpb);
        k_final<8192><<<BATCH, 512, 0, stream>>>(in, meta, cnt1, cand0, cand1, out);
    } else {
        // Small-workspace fallback (~400 KB). cnt0 (~5243) exceeds CAP=1024 so
        // K2 routes through the histogram threshold -> ~100-130 candidates.
        const int CAP = 1024, HBINS = 1024, HSHIFT = 8;
        const size_t histB = (size_t)BATCH * HBINS * 4;
        uint32_t* hist = (uint32_t*)ws;
        uint32_t* cnt0 = (uint32_t*)(ws + histB);
        uint32_t* cnt1 = (uint32_t*)(ws + histB + 64);
        uint4*    meta = (uint4*)(ws + histB + 128);
        u64* cand0 = (u64*)(ws + histB + 128 + 256);
        u64* cand1 = (u64*)(ws + histB + 128 + 256 + (size_t)BATCH * CAP * 8);

        hipMemsetAsync(d_ws, 0, histB + 128, stream);
        dim3 gs(bpb, BATCH), blk(256);
        k_hist_collect<<<gs, blk, 0, stream>>>(in, hist, cnt0, cand0, CAP, HBINS, HSHIFT, bpb);
        k_meta<<<BATCH, 256, 0, stream>>>(hist, cnt0, meta, CAP, HBINS, HSHIFT);
        k_collect2<<<gs, blk, 0, stream>>>(in, meta, cnt1, cand1, CAP, bpb);
        k_final<1024><<<BATCH, 512, 0, stream>>>(in, meta, cnt1, cand0, cand1, out);
    }
}

// Round 2
// 537.420 us; speedup vs baseline: 2.5524x; 2.5524x over previous
//
#include <hip/hip_runtime.h>
#include <stdint.h>

// Problem constants (fixed by the reference: [16, 84, 256, 256] f32)
#define BATCH   16
#define C_CLS   80
#define CH_TOT  84
#define HDIM    256
#define WDIM    256
#define HW      65536            // 256*256
#define NCLS    (C_CLS * HW)     // 5,242,880 class elements per batch
#define NQ      (NCLS / 4)       // 1,310,720 float4 quads per batch
#define TOPK    100
#define MIN_CONF 0.1f

// Primary filter threshold: expected ~5243 candidates/batch on U[0,1) data.
#define T0F     0.999f
// Histogram lower bound (fallback path only).
#define T1_MONO 0xBF7D70A4u   // mono(bits(0.99f))

#define LCAP    256           // per-block LDS candidate cap

typedef unsigned long long u64;

__device__ __forceinline__ uint32_t mono32(uint32_t u) {
    return u ^ ((uint32_t)((int32_t)u >> 31) | 0x80000000u);
}
__device__ __forceinline__ u64 umax64(u64 a, u64 b) { return a > b ? a : b; }

// ---------------------------------------------------------------------------
// K1: single streaming pass. Collect keys of elements >= 0.999 via LDS list,
// ONE returning global atomic per block (counters padded to 64B/batch).
// No histogram work on the hot path.
// ---------------------------------------------------------------------------
__global__ __launch_bounds__(256)
void k_scan(const float* __restrict__ in, uint32_t* __restrict__ cnt0,
            uint32_t* __restrict__ ovf, u64* __restrict__ cand0,
            int cap, int bpb) {
    const int b = blockIdx.y;
    const float4* __restrict__ src =
        (const float4*)(in + (size_t)b * CH_TOT * HW);

    __shared__ uint32_t lcnt;
    __shared__ uint32_t sbase;
    __shared__ u64 lkeys[LCAP];
    if (threadIdx.x == 0) lcnt = 0;
    __syncthreads();

    const int qblk = NQ / bpb;               // quads per block
    const int q0 = blockIdx.x * qblk + threadIdx.x;
    const int iters = qblk / 256;            // per-thread quads

#define PROC(v, q)                                                          \
    {                                                                       \
        const float mx = fmaxf(fmaxf(v.x, v.y), fmaxf(v.z, v.w));           \
        if (mx >= T0F) {                                                    \
            const uint32_t i0 = (uint32_t)(q) * 4u;                         \
            const float e0 = v.x, e1 = v.y, e2 = v.z, e3 = v.w;             \
            if (e0 >= T0F) {                                                \
                uint32_t s = atomicAdd(&lcnt, 1u);                          \
                if (s < LCAP) lkeys[s] = ((u64)mono32(__float_as_uint(e0)) << 32) | (u64)(0xFFFFFFFFu - (i0 + 0)); \
            }                                                               \
            if (e1 >= T0F) {                                                \
                uint32_t s = atomicAdd(&lcnt, 1u);                          \
                if (s < LCAP) lkeys[s] = ((u64)mono32(__float_as_uint(e1)) << 32) | (u64)(0xFFFFFFFFu - (i0 + 1)); \
            }                                                               \
            if (e2 >= T0F) {                                                \
                uint32_t s = atomicAdd(&lcnt, 1u);                          \
                if (s < LCAP) lkeys[s] = ((u64)mono32(__float_as_uint(e2)) << 32) | (u64)(0xFFFFFFFFu - (i0 + 2)); \
            }                                                               \
            if (e3 >= T0F) {                                                \
                uint32_t s = atomicAdd(&lcnt, 1u);                          \
                if (s < LCAP) lkeys[s] = ((u64)mono32(__float_as_uint(e3)) << 32) | (u64)(0xFFFFFFFFu - (i0 + 3)); \
            }                                                               \
        }                                                                   \
    }

    for (int i = 0; i < iters; i += 4) {
        const int qa = q0 + (i + 0) * 256;
        const int qb = q0 + (i + 1) * 256;
        const int qc = q0 + (i + 2) * 256;
        const int qd = q0 + (i + 3) * 256;
        float4 va = src[qa];
        float4 vb = src[qb];
        float4 vc = src[qc];
        float4 vd = src[qd];
        PROC(va, qa)
        PROC(vb, qb)
        PROC(vc, qc)
        PROC(vd, qd)
    }
#undef PROC

    __syncthreads();
    if (threadIdx.x == 0) {
        const uint32_t n = lcnt;
        const uint32_t nn = n < LCAP ? n : LCAP;
        const uint32_t base = atomicAdd(&cnt0[b * 16], nn);
        sbase = base;
        if (n > LCAP || base + nn > (uint32_t)cap) atomicOr(&ovf[b * 16], 1u);
    }
    __syncthreads();
    const uint32_t nn = lcnt < LCAP ? lcnt : LCAP;
    for (uint32_t i = threadIdx.x; i < nn; i += 256) {
        const uint32_t s = sbase + i;
        if (s < (uint32_t)cap) cand0[(size_t)b * cap + s] = lkeys[i];
    }
}

// ---------------------------------------------------------------------------
// Fallback histogram pass — early-exits per batch when buffer 0 suffices
// (the common case: costs only the launch + 16 flag reads).
// ---------------------------------------------------------------------------
__global__ __launch_bounds__(256)
void k_hist_fb(const float* __restrict__ in, const uint32_t* __restrict__ cnt0,
               const uint32_t* __restrict__ ovf, uint32_t* __restrict__ hist,
               int cap, int hbins, int hshift, int bpb) {
    const int b = blockIdx.y;
    const uint32_t c0 = cnt0[b * 16];
    if (ovf[b * 16] == 0u && c0 >= TOPK && c0 <= (uint32_t)cap) return;

    uint32_t* __restrict__ histb = hist + (size_t)b * hbins;
    const float4* __restrict__ src =
        (const float4*)(in + (size_t)b * CH_TOT * HW);
    const int qblk = NQ / bpb;
    const int q0 = blockIdx.x * qblk + threadIdx.x;
    const int iters = qblk / 256;
    for (int i = 0; i < iters; ++i) {
        const int q = q0 + i * 256;
        float4 v = src[q];
        uint32_t us[4] = { __float_as_uint(v.x), __float_as_uint(v.y),
                           __float_as_uint(v.z), __float_as_uint(v.w) };
#pragma unroll
        for (int j = 0; j < 4; ++j) {
            uint32_t m = mono32(us[j]);
            if (m >= T1_MONO) {
                uint32_t bin = (m - T1_MONO) >> hshift;
                if (bin >= (uint32_t)hbins) bin = hbins - 1;
                atomicAdd(&histb[bin], 1u);
            }
        }
    }
}

// ---------------------------------------------------------------------------
// K2: per-batch decision. meta = {use_fallback, n0, fallback_thresh, 0}
// ---------------------------------------------------------------------------
__global__ __launch_bounds__(256)
void k_meta(const uint32_t* __restrict__ hist, const uint32_t* __restrict__ cnt0,
            const uint32_t* __restrict__ ovf, uint4* __restrict__ meta,
            int cap, int hbins, int hshift) {
    const int b = blockIdx.x;
    const uint32_t c0 = cnt0[b * 16];
    if (ovf[b * 16] == 0u && c0 >= TOPK && c0 <= (uint32_t)cap) {
        if (threadIdx.x == 0) meta[b] = make_uint4(0u, c0, 0u, 0u);
        return;
    }
    // Fallback: suffix-scan the histogram from the top for a threshold with
    // cumulative count >= TOPK.
    __shared__ uint32_t psum[256];
    const uint32_t* hb = hist + (size_t)b * hbins;
    const int per = hbins / 256;
    uint32_t s = 0;
    for (int i = 0; i < per; ++i) s += hb[threadIdx.x * per + i];
    psum[threadIdx.x] = s;
    __syncthreads();
    if (threadIdx.x == 0) {
        uint32_t cum = 0, thresh = 0;
        int done = 0;
        for (int t = 255; t >= 0 && !done; --t) {
            if (cum + psum[t] >= TOPK) {
                for (int i = per - 1; i >= 0; --i) {
                    const int bin = t * per + i;
                    cum += hb[bin];
                    if (cum >= TOPK) {
                        thresh = T1_MONO + ((uint32_t)bin << hshift);
                        done = 1;
                        break;
                    }
                }
            } else {
                cum += psum[t];
            }
        }
        if (!done) thresh = 0u;  // degenerate data: collect everything (capped)
        meta[b] = make_uint4(1u, 0u, thresh, 0u);
    }
}

// ---------------------------------------------------------------------------
// K3: fallback collect (early-exits when buffer 0 suffices — the common case)
// ---------------------------------------------------------------------------
__global__ __launch_bounds__(256)
void k_collect2(const float* __restrict__ in, const uint4* __restrict__ meta,
                uint32_t* __restrict__ cnt1, u64* __restrict__ cand1,
                int cap, int bpb) {
    const int b = blockIdx.y;
    const uint4 m = meta[b];
    if (m.x != 1u) return;
    const uint32_t thresh = m.z;
    const float4* __restrict__ src =
        (const float4*)(in + (size_t)b * CH_TOT * HW);
    const int qblk = NQ / bpb;
    const int q0 = blockIdx.x * qblk + threadIdx.x;
    const int iters = qblk / 256;
    for (int i = 0; i < iters; ++i) {
        const int q = q0 + i * 256;
        float4 v = src[q];
        uint32_t us[4] = { __float_as_uint(v.x), __float_as_uint(v.y),
                           __float_as_uint(v.z), __float_as_uint(v.w) };
        const uint32_t idx0 = (uint32_t)q * 4u;
#pragma unroll
        for (int j = 0; j < 4; ++j) {
            uint32_t mo = mono32(us[j]);
            if (mo >= thresh) {
                uint32_t slot = atomicAdd(&cnt1[b * 16], 1u);
                if (slot < (uint32_t)cap) {
                    u64 key = ((u64)mo << 32) | (u64)(0xFFFFFFFFu - (idx0 + j));
                    cand1[(size_t)b * cap + slot] = key;
                }
            }
        }
    }
}

// ---------------------------------------------------------------------------
// K4: per-batch exact top-100 (desc by 64-bit key) + decode + gather + write.
// ---------------------------------------------------------------------------
template <int CAP>
__global__ __launch_bounds__(512)
void k_final(const float* __restrict__ in, const uint4* __restrict__ meta,
             const uint32_t* __restrict__ cnt1, const u64* __restrict__ cand0,
             const u64* __restrict__ cand1, float* __restrict__ out) {
    constexpr int NT = 512;
    constexpr int KPT = CAP / NT;
    const int b = blockIdx.x;
    const int t = threadIdx.x;
    const int wave = t >> 6, lane = t & 63;

    const uint4 m = meta[b];
    const u64* cand;
    uint32_t n;
    if (m.x == 0u) { cand = cand0 + (size_t)b * CAP; n = m.y; }
    else           { cand = cand1 + (size_t)b * CAP; n = min(cnt1[b * 16], (uint32_t)CAP); }

    u64 key[KPT];
#pragma unroll
    for (int j = 0; j < KPT; ++j) {
        const uint32_t i = (uint32_t)(t + j * NT);   // coalesced
        key[j] = (i < n) ? cand[i] : 0ull;
    }
    u64 lmax = 0;
#pragma unroll
    for (int j = 0; j < KPT; ++j) lmax = umax64(lmax, key[j]);

    __shared__ u64 wmax[NT / 64];
    __shared__ u64 gsel;
    __shared__ u64 sel[TOPK];

    for (int r = 0; r < TOPK; ++r) {
        u64 wm = lmax;
#pragma unroll
        for (int d = 1; d < 64; d <<= 1) wm = umax64(wm, __shfl_xor(wm, d, 64));
        if (lane == 0) wmax[wave] = wm;
        __syncthreads();
        if (t == 0) {
            u64 g = wmax[0];
#pragma unroll
            for (int w2 = 1; w2 < NT / 64; ++w2) g = umax64(g, wmax[w2]);
            gsel = g;
            sel[r] = g;
        }
        __syncthreads();
        const u64 g = gsel;
        if (g != 0ull && lmax == g) {   // keys are distinct: exactly one owner
#pragma unroll
            for (int j = 0; j < KPT; ++j) if (key[j] == g) key[j] = 0ull;
            lmax = 0;
#pragma unroll
            for (int j = 0; j < KPT; ++j) lmax = umax64(lmax, key[j]);
        }
    }
    __syncthreads();

    if (t < TOPK) {
        const u64 kk = sel[t];
        float* o = out + ((size_t)b * TOPK + t) * 6;
        float vals[6] = {0.f, 0.f, 0.f, 0.f, 0.f, 0.f};
        if (kk != 0ull) {
            const uint32_t mo = (uint32_t)(kk >> 32);
            const uint32_t bits = (mo & 0x80000000u) ? (mo & 0x7FFFFFFFu) : ~mo;
            const float conf = __uint_as_float(bits);
            if (conf >= MIN_CONF) {
                const uint32_t idx = 0xFFFFFFFFu - (uint32_t)(kk & 0xFFFFFFFFu);
                const uint32_t cls = idx >> 16;
                const uint32_t yy = (idx >> 8) & 255u;
                const uint32_t xx = idx & 255u;
                const float* base = in + (size_t)b * CH_TOT * HW + yy * WDIM + xx;
                const float offy = base[(size_t)(C_CLS + 0) * HW];
                const float offx = base[(size_t)(C_CLS + 1) * HW];
                const float hh   = base[(size_t)(C_CLS + 2) * HW];
                const float ww   = base[(size_t)(C_CLS + 3) * HW];
                vals[0] = (float)yy + offy;
                vals[1] = (float)xx + offx;
                vals[2] = hh;
                vals[3] = ww;
                vals[4] = (float)cls;
                vals[5] = conf;
            }
        }
#pragma unroll
        for (int j = 0; j < 6; ++j) o[j] = vals[j];
    }
}

// ---------------------------------------------------------------------------
// Workspace layout:
//   hist   : BATCH*HBINS*4
//   cnt0   : BATCH*64 B (padded, 1 counter per 64B line)
//   cnt1   : BATCH*64 B
//   ovf    : BATCH*64 B
//   meta   : BATCH*16 B
//   cand0  : BATCH*CAP*8
//   cand1  : BATCH*CAP*8
// ---------------------------------------------------------------------------
extern "C" void kernel_launch(void* const* d_in, const int* in_sizes, int n_in,
                              void* d_out, int out_size, void* d_ws, size_t ws_size,
                              hipStream_t stream) {
    const float* in = (const float*)d_in[0];
    float* out = (float*)d_out;
    uint8_t* ws = (uint8_t*)d_ws;

    const int bpb = 320;  // blocks per batch for streaming passes

    const size_t cntB = (size_t)BATCH * 64;  // 1 KB each
    const size_t metaB = (size_t)BATCH * 16;

    const size_t need_big = (size_t)BATCH * 4096 * 4 + 3 * cntB + metaB
                          + 2ull * BATCH * 8192 * 8;

    if (ws_size >= need_big) {
        const int CAP = 8192, HBINS = 4096, HSHIFT = 6;
        const size_t histB = (size_t)BATCH * HBINS * 4;
        uint32_t* hist = (uint32_t*)ws;
        uint32_t* cnt0 = (uint32_t*)(ws + histB);
        uint32_t* cnt1 = (uint32_t*)(ws + histB + cntB);
        uint32_t* ovf  = (uint32_t*)(ws + histB + 2 * cntB);
        uint4*    meta = (uint4*)(ws + histB + 3 * cntB);
        u64* cand0 = (u64*)(ws + histB + 3 * cntB + metaB);
        u64* cand1 = (u64*)(ws + histB + 3 * cntB + metaB + (size_t)BATCH * CAP * 8);

        hipMemsetAsync(d_ws, 0, histB + 3 * cntB, stream);
        dim3 gs(bpb, BATCH), blk(256);
        k_scan<<<gs, blk, 0, stream>>>(in, cnt0, ovf, cand0, CAP, bpb);
        k_hist_fb<<<gs, blk, 0, stream>>>(in, cnt0, ovf, hist, CAP, HBINS, HSHIFT, bpb);
        k_meta<<<BATCH, 256, 0, stream>>>(hist, cnt0, ovf, meta, CAP, HBINS, HSHIFT);
        k_collect2<<<gs, blk, 0, stream>>>(in, meta, cnt1, cand1, CAP, bpb);
        k_final<8192><<<BATCH, 512, 0, stream>>>(in, meta, cnt1, cand0, cand1, out);
    } else {
        // Small-workspace fallback (~420 KB). cnt0 (~5243) exceeds CAP=1024 so
        // the overflow flag routes through the histogram threshold path.
        const int CAP = 1024, HBINS = 1024, HSHIFT = 8;
        const size_t histB = (size_t)BATCH * HBINS * 4;
        uint32_t* hist = (uint32_t*)ws;
        uint32_t* cnt0 = (uint32_t*)(ws + histB);
        uint32_t* cnt1 = (uint32_t*)(ws + histB + cntB);
        uint32_t* ovf  = (uint32_t*)(ws + histB + 2 * cntB);
        uint4*    meta = (uint4*)(ws + histB + 3 * cntB);
        u64* cand0 = (u64*)(ws + histB + 3 * cntB + metaB);
        u64* cand1 = (u64*)(ws + histB + 3 * cntB + metaB + (size_t)BATCH * CAP * 8);

        hipMemsetAsync(d_ws, 0, histB + 3 * cntB, stream);
        dim3 gs(bpb, BATCH), blk(256);
        k_scan<<<gs, blk, 0, stream>>>(in, cnt0, ovf, cand0, CAP, bpb);
        k_hist_fb<<<gs, blk, 0, stream>>>(in, cnt0, ovf, hist, CAP, HBINS, HSHIFT, bpb);
        k_meta<<<BATCH, 256, 0, stream>>>(hist, cnt0, ovf, meta, CAP, HBINS, HSHIFT);
        k_collect2<<<gs, blk, 0, stream>>>(in, meta, cnt1, cand1, CAP, bpb);
        k_final<1024><<<BATCH, 512, 0, stream>>>(in, meta, cnt1, cand0, cand1, out);
    }
}

// Round 4
// 483.693 us; speedup vs baseline: 2.8360x; 1.1111x over previous
//
#include <hip/hip_runtime.h>
#include <stdint.h>
#include <string.h>

// Problem constants (fixed by the reference: [16, 84, 256, 256] f32)
#define BATCH   16
#define C_CLS   80
#define CH_TOT  84
#define HDIM    256
#define WDIM    256
#define HW      65536            // 256*256
#define NCLS    (C_CLS * HW)     // 5,242,880 class elements per batch
#define NQ      (NCLS / 4)       // 1,310,720 float4 quads per batch
#define TOPK    100
#define MIN_CONF 0.1f

// Histogram lower bound for the degenerate-data fallback (mono(bits(0.99f)))
#define T1_MONO 0xBF7D70A4u

#define LCAP    256              // per-block LDS candidate cap in k_scan
#define BPB     160              // blocks per batch: NQ/BPB = 8192 quads/block

typedef unsigned long long u64;

__device__ __forceinline__ uint32_t mono32(uint32_t u) {
    return u ^ ((uint32_t)((int32_t)u >> 31) | 0x80000000u);
}
__device__ __forceinline__ u64 umax64(u64 a, u64 b) { return a > b ? a : b; }

// ---------------------------------------------------------------------------
// K0: zero the padded per-batch counters (cnt0, cnt1, ovf: 16 batches x 64B)
// ---------------------------------------------------------------------------
__global__ __launch_bounds__(256)
void k_init(uint32_t* __restrict__ cnt0, uint32_t* __restrict__ cnt1,
            uint32_t* __restrict__ ovf) {
    const int t = threadIdx.x;   // 256 threads == BATCH*16 u32 per array
    cnt0[t] = 0u;
    cnt1[t] = 0u;
    ovf[t]  = 0u;
}

// ---------------------------------------------------------------------------
// K1: single streaming pass over the class region. Collect keys of elements
// >= t0f via an LDS list; ONE returning global atomic per block.
// ---------------------------------------------------------------------------
__global__ __launch_bounds__(256)
void k_scan(const float* __restrict__ in, uint32_t* __restrict__ cnt0,
            uint32_t* __restrict__ ovf, u64* __restrict__ cand0,
            int cap, float t0f) {
    const int b = blockIdx.y;
    const float4* __restrict__ src =
        (const float4*)(in + (size_t)b * CH_TOT * HW);

    __shared__ uint32_t lcnt;
    __shared__ uint32_t sbase;
    __shared__ u64 lkeys[LCAP];
    if (threadIdx.x == 0) lcnt = 0;
    __syncthreads();

    const int qblk = NQ / BPB;               // 8192 quads per block
    const int q0 = blockIdx.x * qblk + threadIdx.x;
    const int iters = qblk / 256;            // 32 per-thread quads

    for (int i = 0; i < iters; i += 8) {
        float4 v[8];
        int q[8];
#pragma unroll
        for (int u = 0; u < 8; ++u) {
            q[u] = q0 + (i + u) * 256;
            v[u] = src[q[u]];
        }
#pragma unroll
        for (int u = 0; u < 8; ++u) {
            const float4 vv = v[u];
            const float mx = fmaxf(fmaxf(vv.x, vv.y), fmaxf(vv.z, vv.w));
            if (mx >= t0f) {
                const uint32_t i0 = (uint32_t)q[u] * 4u;
                const float e[4] = { vv.x, vv.y, vv.z, vv.w };
#pragma unroll
                for (int j = 0; j < 4; ++j) {
                    if (e[j] >= t0f) {
                        uint32_t s = atomicAdd(&lcnt, 1u);
                        if (s < LCAP)
                            lkeys[s] = ((u64)mono32(__float_as_uint(e[j])) << 32)
                                     | (u64)(0xFFFFFFFFu - (i0 + j));
                    }
                }
            }
        }
    }

    __syncthreads();
    if (threadIdx.x == 0) {
        const uint32_t n = lcnt;
        const uint32_t nn = n < LCAP ? n : LCAP;
        const uint32_t base = atomicAdd(&cnt0[b * 16], nn);
        sbase = base;
        if (n > LCAP || base + nn > (uint32_t)cap) atomicOr(&ovf[b * 16], 1u);
    }
    __syncthreads();
    const uint32_t nn = lcnt < LCAP ? lcnt : LCAP;
    for (uint32_t i = threadIdx.x; i < nn; i += 256) {
        const uint32_t s = sbase + i;
        if (s < (uint32_t)cap) cand0[(size_t)b * cap + s] = lkeys[i];
    }
}

// ---------------------------------------------------------------------------
// K2: per-batch decision. meta = {use_fallback, n0, fallback_thresh, 0}.
// Fallback path (never taken on this data) builds its own per-batch LDS
// histogram by streaming the batch with one block — slow but self-contained,
// no global histogram buffer or pre-zeroing needed.
// ---------------------------------------------------------------------------
__global__ __launch_bounds__(256)
void k_meta(const float* __restrict__ in, const uint32_t* __restrict__ cnt0,
            const uint32_t* __restrict__ ovf, uint4* __restrict__ meta,
            int cap) {
    const int b = blockIdx.x;
    const uint32_t c0 = cnt0[b * 16];
    if (ovf[b * 16] == 0u && c0 >= TOPK && c0 <= (uint32_t)cap) {
        if (threadIdx.x == 0) meta[b] = make_uint4(0u, c0, 0u, 0u);
        return;
    }
    __shared__ uint32_t hist[4096];
    for (int i = threadIdx.x; i < 4096; i += 256) hist[i] = 0u;
    __syncthreads();
    const float4* __restrict__ src =
        (const float4*)(in + (size_t)b * CH_TOT * HW);
    for (int q = threadIdx.x; q < NQ; q += 256) {
        float4 v = src[q];
        uint32_t us[4] = { __float_as_uint(v.x), __float_as_uint(v.y),
                           __float_as_uint(v.z), __float_as_uint(v.w) };
#pragma unroll
        for (int j = 0; j < 4; ++j) {
            uint32_t m = mono32(us[j]);
            if (m >= T1_MONO) {
                uint32_t bin = (m - T1_MONO) >> 6;
                if (bin > 4095u) bin = 4095u;
                atomicAdd(&hist[bin], 1u);
            }
        }
    }
    __syncthreads();
    if (threadIdx.x == 0) {
        uint32_t cum = 0, thresh = 0;
        int done = 0;
        for (int t = 4095; t >= 0; --t) {
            cum += hist[t];
            if (cum >= TOPK) {
                thresh = T1_MONO + ((uint32_t)t << 6);
                done = 1;
                break;
            }
        }
        if (!done) thresh = 0u;   // degenerate: collect everything (capped)
        meta[b] = make_uint4(1u, 0u, thresh, 0u);
    }
}

// ---------------------------------------------------------------------------
// K3: fallback collect (early-exits when buffer 0 suffices — the common case)
// ---------------------------------------------------------------------------
__global__ __launch_bounds__(256)
void k_collect2(const float* __restrict__ in, const uint4* __restrict__ meta,
                uint32_t* __restrict__ cnt1, u64* __restrict__ cand1,
                int cap) {
    const int b = blockIdx.y;
    const uint4 m = meta[b];
    if (m.x != 1u) return;
    const uint32_t thresh = m.z;
    const float4* __restrict__ src =
        (const float4*)(in + (size_t)b * CH_TOT * HW);
    const int qblk = NQ / BPB;
    const int q0 = blockIdx.x * qblk + threadIdx.x;
    const int iters = qblk / 256;
    for (int i = 0; i < iters; ++i) {
        const int q = q0 + i * 256;
        float4 v = src[q];
        uint32_t us[4] = { __float_as_uint(v.x), __float_as_uint(v.y),
                           __float_as_uint(v.z), __float_as_uint(v.w) };
        const uint32_t idx0 = (uint32_t)q * 4u;
#pragma unroll
        for (int j = 0; j < 4; ++j) {
            uint32_t mo = mono32(us[j]);
            if (mo >= thresh) {
                uint32_t slot = atomicAdd(&cnt1[b * 16], 1u);
                if (slot < (uint32_t)cap) {
                    u64 key = ((u64)mo << 32) | (u64)(0xFFFFFFFFu - (idx0 + j));
                    cand1[(size_t)b * cap + slot] = key;
                }
            }
        }
    }
}

// ---------------------------------------------------------------------------
// K4: per-batch exact top-100 (desc by 64-bit key) + decode + gather + write.
// Fast path: LDS-histogram rank selection (bin keys by high bits, suffix-scan
// to the bin containing rank 100, compact survivors, exact O(S^2/NT) rank).
// Guarded fallback: the 100-round block argmax (for degenerate key sets).
// ---------------------------------------------------------------------------
template <int CAP>
__global__ __launch_bounds__(512)
void k_final(const float* __restrict__ in, const uint4* __restrict__ meta,
             const uint32_t* __restrict__ cnt1, const u64* __restrict__ cand0,
             const u64* __restrict__ cand1, float* __restrict__ out,
             uint32_t binbase, int binshift) {
    constexpr int NT = 512;
    constexpr int KPT = CAP / NT;
    constexpr int SELCAP = 512;
    const int b = blockIdx.x;
    const int t = threadIdx.x;
    const int wave = t >> 6, lane = t & 63;

    const uint4 m = meta[b];
    const u64* cand;
    uint32_t n;
    if (m.x == 0u) { cand = cand0 + (size_t)b * CAP; n = m.y; }
    else           { cand = cand1 + (size_t)b * CAP; n = min(cnt1[b * 16], (uint32_t)CAP); }
    if (n > (uint32_t)CAP) n = (uint32_t)CAP;

    u64 key[KPT];
#pragma unroll
    for (int j = 0; j < KPT; ++j) {
        const uint32_t i = (uint32_t)(t + j * NT);   // coalesced
        key[j] = (i < n) ? cand[i] : 0ull;
    }

    __shared__ uint32_t hist[4096];
    __shared__ uint32_t psum[NT];
    __shared__ u64 skeys[SELCAP];
    __shared__ uint32_t scnt;
    __shared__ u64 sel[TOPK];
    __shared__ uint32_t sB, sS;

    for (int i = t; i < 4096; i += NT) hist[i] = 0u;
    if (t < TOPK) sel[t] = 0ull;
    if (t == 0) scnt = 0u;
    __syncthreads();

#define KBIN(kk)                                                            \
    ({ const uint32_t mo_ = (uint32_t)((kk) >> 32);                         \
       uint32_t bin_ = 0u;                                                  \
       if (mo_ >= binbase) {                                                \
           bin_ = (mo_ - binbase) >> binshift;                              \
           if (bin_ > 4095u) bin_ = 4095u;                                  \
       }                                                                    \
       bin_; })

#pragma unroll
    for (int j = 0; j < KPT; ++j)
        if (key[j] != 0ull) atomicAdd(&hist[KBIN(key[j])], 1u);
    __syncthreads();

    // suffix-scan: find smallest bin B with sum_{bin>=B} hist[bin] >= TOPK
    uint32_t ps = 0;
#pragma unroll
    for (int i = 0; i < 8; ++i) ps += hist[t * 8 + i];
    psum[t] = ps;
    __syncthreads();
    if (t == 0) {
        uint32_t cum = 0;
        uint32_t B = 0, S = 0;
        int done = 0;
        for (int seg = NT - 1; seg >= 0 && !done; --seg) {
            if (cum + psum[seg] >= TOPK) {
                for (int i = 7; i >= 0; --i) {
                    const int bin = seg * 8 + i;
                    cum += hist[bin];
                    if (cum >= TOPK) { B = (uint32_t)bin; S = cum; done = 1; break; }
                }
            } else {
                cum += psum[seg];
            }
        }
        if (!done) { B = 0u; S = cum; }   // fewer than TOPK keys total
        sB = B; sS = S;
    }
    __syncthreads();
    const uint32_t B = sB, S = sS;

    if (S <= (uint32_t)SELCAP) {
        // compact survivors (count with bin >= B is exactly S <= SELCAP)
#pragma unroll
        for (int j = 0; j < KPT; ++j) {
            if (key[j] != 0ull && KBIN(key[j]) >= B) {
                uint32_t s = atomicAdd(&scnt, 1u);
                if (s < (uint32_t)SELCAP) skeys[s] = key[j];
            }
        }
        __syncthreads();
        const uint32_t Sc = scnt < (uint32_t)SELCAP ? scnt : (uint32_t)SELCAP;
        for (uint32_t i = t; i < Sc; i += NT) {
            const u64 kk = skeys[i];
            uint32_t r = 0;
            for (uint32_t j2 = 0; j2 < Sc; ++j2) r += (skeys[j2] > kk) ? 1u : 0u;
            if (r < TOPK) sel[r] = kk;
        }
        __syncthreads();
    } else {
        // degenerate distribution: exact 100-round block argmax
        u64 lmax = 0;
#pragma unroll
        for (int j = 0; j < KPT; ++j) lmax = umax64(lmax, key[j]);
        __shared__ u64 wmax[NT / 64];
        __shared__ u64 gsel;
        for (int r = 0; r < TOPK; ++r) {
            u64 wm = lmax;
#pragma unroll
            for (int d = 1; d < 64; d <<= 1) wm = umax64(wm, __shfl_xor(wm, d, 64));
            if (lane == 0) wmax[wave] = wm;
            __syncthreads();
            if (t == 0) {
                u64 g = wmax[0];
#pragma unroll
                for (int w2 = 1; w2 < NT / 64; ++w2) g = umax64(g, wmax[w2]);
                gsel = g;
                sel[r] = g;
            }
            __syncthreads();
            const u64 g = gsel;
            if (g != 0ull && lmax == g) {   // keys distinct: exactly one owner
#pragma unroll
                for (int j = 0; j < KPT; ++j) if (key[j] == g) key[j] = 0ull;
                lmax = 0;
#pragma unroll
                for (int j = 0; j < KPT; ++j) lmax = umax64(lmax, key[j]);
            }
        }
        __syncthreads();
    }
#undef KBIN

    if (t < TOPK) {
        const u64 kk = sel[t];
        float* o = out + ((size_t)b * TOPK + t) * 6;
        float vals[6] = {0.f, 0.f, 0.f, 0.f, 0.f, 0.f};
        if (kk != 0ull) {
            const uint32_t mo = (uint32_t)(kk >> 32);
            const uint32_t bits = (mo & 0x80000000u) ? (mo & 0x7FFFFFFFu) : ~mo;
            const float conf = __uint_as_float(bits);
            if (conf >= MIN_CONF) {
                const uint32_t idx = 0xFFFFFFFFu - (uint32_t)(kk & 0xFFFFFFFFu);
                const uint32_t cls = idx >> 16;
                const uint32_t yy = (idx >> 8) & 255u;
                const uint32_t xx = idx & 255u;
                const float* base = in + (size_t)b * CH_TOT * HW + yy * WDIM + xx;
                const float offy = base[(size_t)(C_CLS + 0) * HW];
                const float offx = base[(size_t)(C_CLS + 1) * HW];
                const float hh   = base[(size_t)(C_CLS + 2) * HW];
                const float ww   = base[(size_t)(C_CLS + 3) * HW];
                vals[0] = (float)yy + offy;
                vals[1] = (float)xx + offx;
                vals[2] = hh;
                vals[3] = ww;
                vals[4] = (float)cls;
                vals[5] = conf;
            }
        }
#pragma unroll
        for (int j = 0; j < 6; ++j) o[j] = vals[j];
    }
}

// ---------------------------------------------------------------------------
// Workspace layout:
//   cnt0 : BATCH*64 B   (1 counter per 64B line)
//   cnt1 : BATCH*64 B
//   ovf  : BATCH*64 B
//   meta : BATCH*16 B
//   cand0: BATCH*CAP*8
//   cand1: BATCH*CAP*8
// ---------------------------------------------------------------------------
extern "C" void kernel_launch(void* const* d_in, const int* in_sizes, int n_in,
                              void* d_out, int out_size, void* d_ws, size_t ws_size,
                              hipStream_t stream) {
    const float* in = (const float*)d_in[0];
    float* out = (float*)d_out;
    uint8_t* ws = (uint8_t*)d_ws;

    const size_t cntB = (size_t)BATCH * 64;
    const size_t metaB = (size_t)BATCH * 16;

    auto monoh = [](float f) -> uint32_t {
        uint32_t u;
        memcpy(&u, &f, 4);
        return u ^ ((uint32_t)((int32_t)u >> 31) | 0x80000000u);
    };

    const size_t need_big = 3 * cntB + metaB + 2ull * BATCH * 8192 * 8;

    dim3 gs(BPB, BATCH), blk(256);

    if (ws_size >= need_big) {
        const int CAP = 8192;
        const float T0 = 0.999f;           // ~5243 expected candidates/batch
        uint32_t* cnt0 = (uint32_t*)ws;
        uint32_t* cnt1 = (uint32_t*)(ws + cntB);
        uint32_t* ovf  = (uint32_t*)(ws + 2 * cntB);
        uint4*    meta = (uint4*)(ws + 3 * cntB);
        u64* cand0 = (u64*)(ws + 3 * cntB + metaB);
        u64* cand1 = (u64*)(ws + 3 * cntB + metaB + (size_t)BATCH * CAP * 8);

        k_init<<<1, 256, 0, stream>>>(cnt0, cnt1, ovf);
        k_scan<<<gs, blk, 0, stream>>>(in, cnt0, ovf, cand0, CAP, T0);
        k_meta<<<BATCH, 256, 0, stream>>>(in, cnt0, ovf, meta, CAP);
        k_collect2<<<gs, blk, 0, stream>>>(in, meta, cnt1, cand1, CAP);
        k_final<8192><<<BATCH, 512, 0, stream>>>(in, meta, cnt1, cand0, cand1,
                                                 out, monoh(T0), 3);
    } else {
        // Small-workspace config (~270 KB): higher threshold so candidates
        // fit CAP=1024 (expected ~262/batch).
        const int CAP = 1024;
        const float T0 = 0.99995f;
        uint32_t* cnt0 = (uint32_t*)ws;
        uint32_t* cnt1 = (uint32_t*)(ws + cntB);
        uint32_t* ovf  = (uint32_t*)(ws + 2 * cntB);
        uint4*    meta = (uint4*)(ws + 3 * cntB);
        u64* cand0 = (u64*)(ws + 3 * cntB + metaB);
        u64* cand1 = (u64*)(ws + 3 * cntB + metaB + (size_t)BATCH * CAP * 8);

        k_init<<<1, 256, 0, stream>>>(cnt0, cnt1, ovf);
        k_scan<<<gs, blk, 0, stream>>>(in, cnt0, ovf, cand0, CAP, T0);
        k_meta<<<BATCH, 256, 0, stream>>>(in, cnt0, ovf, meta, CAP);
        k_collect2<<<gs, blk, 0, stream>>>(in, meta, cnt1, cand1, CAP);
        k_final<1024><<<BATCH, 512, 0, stream>>>(in, meta, cnt1, cand0, cand1,
                                                 out, monoh(T0), 0);
    }
}